// Round 18
// baseline (45.333 us; speedup 1.0000x reference)
//
#include <hip/hip_runtime.h>

// UDTCWT fully-fused r18 = r17 anchor (43.9us) + ONE change: early global
// psi/yl stores for D>=16 (MODE1) and last level (MODE2, barrier-free).
// All else byte-identical: one in-place LDS buffer + 32KB psi stage for
// D in {2,4,8}; TS=8192, halo 1152, NT=768, W=15, 74.75KB LDS ->
// 2 blocks/CU, grid 512 exactly resident. All contiguous LDS ops b128.
// B=4, C=8 -> 16 chains, T=65536. Output: yl [4][8][T], yh [8][4][16][T].

static constexpr int B  = 4;
static constexpr int C2 = 16;
static constexpr int T  = 65536;
static constexpr int NT = 768;
static constexpr int TS = 8192;
static constexpr int HB = 1152;
static constexpr int S  = TS + 2 * HB;   // 10496 floats = 41.98 KB

__device__ __forceinline__ float rfl(float x) {
    return __int_as_float(__builtin_amdgcn_readfirstlane(__float_as_int(x)));
}

// LDS-only barrier (measured neutral vs __syncthreads in r11).
__device__ __forceinline__ void bar_lds() {
    asm volatile("s_waitcnt lgkmcnt(0)" ::: "memory");
    __builtin_amdgcn_s_barrier();
}

// Margin chain: lvl1 out 1148; each dilated level consumes 4.5*D:
// 1136(D2) 1116(D4) 1080(D8) 1008(D16) 864(D32) 576(D64) 0(D128).

// ---------- Level 1 (D=1), in-place, 16 outputs (4 quads) per thread ----------
template <int SH>
__device__ __forceinline__ void f_lvl1(
    float* __restrict__ buf,
    const float* __restrict__ h0o, const float* __restrict__ h1o,
    float* __restrict__ psi_g, int gbase, int tid)
{
    float f0[5], f1[7];
#pragma unroll
    for (int k = 0; k < 5; ++k) f0[k] = rfl(h0o[k]);
#pragma unroll
    for (int k = 0; k < 7; ++k) f1[k] = rfl(h1o[k]);

    constexpr int OFF   = SH ? 1 : 2;       // w[i+k+OFF] = x[p0+i+WO+k]
    constexpr int FS    = SH ? 2 : 0;       // phi tap shift
    constexpr int MO    = 1148;
    constexpr int START = HB - MO;          // 4 (%4==0)
    constexpr int NQ    = (TS + 2 * MO) / 4;  // 2622 quads
    constexpr int G     = (NQ + 3) / 4;       // 656 threads
    const bool act = tid < G;

    int p0 = 0;
    float w[24], a[16], bb[16];
    if (act) {
        int qs = tid * 4;
        if (qs > NQ - 4) qs = NQ - 4;       // clamp (dup work, benign)
        p0 = START + qs * 4;
#pragma unroll
        for (int j = 0; j < 6; ++j)
            *(float4*)&w[4 * j] = *(const float4*)&buf[p0 - 4 + 4 * j];
#pragma unroll
        for (int i = 0; i < 16; ++i) {
            float sa = 0.f, sb = 0.f;
#pragma unroll
            for (int k = 0; k < 5; ++k) sa += w[i + k + FS + OFF] * f0[k];
#pragma unroll
            for (int k = 0; k < 7; ++k) sb += w[i + k + OFF] * f1[k];
            a[i] = sa; bb[i] = sb;
        }
    }
    bar_lds();
    if (act) {
#pragma unroll
        for (int qq = 0; qq < 4; ++qq) {
            int p = p0 + qq * 4;            // %4==0
            if ((unsigned)(p - HB) < (unsigned)TS)
                *(float4*)&psi_g[gbase + p] =
                    make_float4(bb[4*qq], bb[4*qq+1], bb[4*qq+2], bb[4*qq+3]);
            const bool inT = (unsigned)(gbase + p) < (unsigned)T;
            *(float4*)&buf[p] = inT
                ? make_float4(a[4*qq], a[4*qq+1], a[4*qq+2], a[4*qq+3])
                : make_float4(0.f, 0.f, 0.f, 0.f);
        }
    }
    bar_lds();
}

// ---------- Dilated level, in-place ----------
// MODE 0: stage psi->P post-barrier (D in {2,4,8}); buf write post-barrier.
// MODE 1: psi->global in COMPUTE phase; buf write post-barrier.
// MODE 2: last level: psi (+yl) ->global in compute phase; NO barriers.
template <int D, int W, int MO, int MODE>
__device__ __forceinline__ void f_level(
    float* __restrict__ buf, float* __restrict__ psi_st,
    const float (&f0)[10], const float (&f1)[10],
    float* __restrict__ psi_g, float* __restrict__ yl_g,
    int gbase, int tid, bool wr_yl)
{
    constexpr int HALF  = 9 * D / 2;
    constexpr int START = HB - MO;
    constexpr int N     = TS + 2 * MO;
    static_assert(N % D == 0, "");
    constexpr int NPD   = N / D;
    constexpr int CPC   = (NPD + W - 1) / W;
    constexpr int G     = D * CPC;
    static_assert(G <= NT, "single chunk per thread required");
    constexpr int LOG2D = (D == 2 ? 1 : D == 4 ? 2 : D == 8 ? 3 :
                           D == 16 ? 4 : D == 32 ? 5 : D == 64 ? 6 : 7);

    float a[W], bb[W];
    int p0 = 0;
    const bool act = tid < G;
    const bool do_phi = (MODE != 2) || wr_yl;   // block-uniform
    if (act) {
        int r  = tid & (D - 1);
        int q  = tid >> LOG2D;
        int ms = q * W;
        if (ms > NPD - W) ms = NPD - W;         // clamp (dup work, benign)
        p0 = START + r + ms * D;

        float v[W + 9];
#pragma unroll
        for (int n = 0; n < W + 9; ++n) v[n] = buf[p0 - HALF + n * D];
#pragma unroll
        for (int m = 0; m < W; ++m) { a[m] = 0.f; bb[m] = 0.f; }
        if (do_phi) {
#pragma unroll
            for (int k = 0; k < 10; ++k)
#pragma unroll
                for (int m = 0; m < W; ++m) {
                    float x = v[m + k];
                    a[m] += x * f0[k]; bb[m] += x * f1[k];
                }
        } else {
#pragma unroll
            for (int k = 0; k < 10; ++k)
#pragma unroll
                for (int m = 0; m < W; ++m) bb[m] += v[m + k] * f1[k];
        }
        if constexpr (MODE >= 1) {
            // psi (and yl) issued during compute phase; bb/a die here
#pragma unroll
            for (int m = 0; m < W; ++m) {
                int p = p0 + m * D;
                if ((unsigned)(p - HB) < (unsigned)TS) psi_g[gbase + p] = bb[m];
            }
            if constexpr (MODE == 2) {
                if (wr_yl) {
#pragma unroll
                    for (int m = 0; m < W; ++m) {
                        int p = p0 + m * D;
                        if ((unsigned)(p - HB) < (unsigned)TS)
                            yl_g[gbase + p] = a[m];
                    }
                }
            }
        }
    }
    if constexpr (MODE == 2) return;    // last level: nothing writes LDS

    bar_lds();
    if (act) {
#pragma unroll
        for (int m = 0; m < W; ++m) {
            int p = p0 + m * D;
            if constexpr (MODE == 0) {
                if ((unsigned)(p - HB) < (unsigned)TS) psi_st[p - HB] = bb[m];
            }
            buf[p] = ((unsigned)(gbase + p) < (unsigned)T) ? a[m] : 0.f;
        }
    }
    bar_lds();
}

// Coalesced copy psi_st -> global (overlaps next level's compute phase).
__device__ __forceinline__ void f_copyout(
    const float* __restrict__ psi_st, float* __restrict__ dst, int tid)
{
    for (int i4 = tid * 4; i4 < TS; i4 += NT * 4)
        *(float4*)&dst[i4] = *(const float4*)&psi_st[i4];
}

__global__ __launch_bounds__(768, 6) void udtcwt_fused(
    const float* __restrict__ x,
    const float* __restrict__ h0o, const float* __restrict__ h1o,
    const float* __restrict__ h0a, const float* __restrict__ h1a,
    const float* __restrict__ h0b, const float* __restrict__ h1b,
    float* __restrict__ out)
{
    __shared__ float A[S];       // 41.98 KB, in-place phi chain
    __shared__ float P[TS];      // 32 KB psi stage

    const int tid   = threadIdx.x;
    const int bid   = blockIdx.x;
    const int tile  = bid & 7;           // 8 tiles of 8192
    const int chain = bid >> 3;          // 0..63
    const int shbit = chain & 1;
    const int cx    = (chain >> 1) & 7;
    const int b     = chain >> 4;
    const int c2    = shbit * 8 + cx;
    const int t0    = tile * TS;
    const int gbase = t0 - HB;           // %4 == 0

    // stage x tile + halo (zeros outside [0,T)); all b128
    const float* xin = x + (size_t)(b * 8 + cx) * T;
    for (int i4 = tid * 4; i4 < S; i4 += NT * 4) {
        int gg = gbase + i4;             // quad fully in or out of [0,T)
        float4 v = ((unsigned)gg < (unsigned)T)
                 ? *(const float4*)&xin[gg]
                 : make_float4(0.f, 0.f, 0.f, 0.f);
        *(float4*)&A[i4] = v;
    }

    float f0[10], f1[10];
    {
        const float* F0 = (c2 & 1) ? h0b : h0a;
        const float* F1 = (c2 & 1) ? h1b : h1a;
#pragma unroll
        for (int k = 0; k < 10; ++k) { f0[k] = rfl(F0[k]); f1[k] = rfl(F1[k]); }
    }

    float* yl_g = out + (size_t)(b * 8 + c2) * T;    // used when c2<8
    float* yh   = out + (size_t)B * 8 * T;
    const size_t LS = (size_t)B * C2 * T;
    float* psi0 = yh + (size_t)(b * C2 + c2) * T;
    const bool wr_yl = (c2 < 8);

    bar_lds();
    if (shbit) f_lvl1<1>(A, h0o, h1o, psi0, gbase, tid);
    else       f_lvl1<0>(A, h0o, h1o, psi0, gbase, tid);

    f_level<  2, 15, 1136, 0>(A, P, f0, f1, nullptr, nullptr, gbase, tid, false);
    f_copyout(P, psi0 + 1 * LS + t0, tid);
    f_level<  4, 15, 1116, 0>(A, P, f0, f1, nullptr, nullptr, gbase, tid, false);
    f_copyout(P, psi0 + 2 * LS + t0, tid);
    f_level<  8, 15, 1080, 0>(A, P, f0, f1, nullptr, nullptr, gbase, tid, false);
    f_copyout(P, psi0 + 3 * LS + t0, tid);
    f_level< 16, 15, 1008, 1>(A, P, f0, f1, psi0 + 4 * LS, nullptr, gbase, tid, false);
    f_level< 32, 15,  864, 1>(A, P, f0, f1, psi0 + 5 * LS, nullptr, gbase, tid, false);
    f_level< 64, 15,  576, 1>(A, P, f0, f1, psi0 + 6 * LS, nullptr, gbase, tid, false);
    f_level<128, 15,    0, 2>(A, P, f0, f1, psi0 + 7 * LS, yl_g,    gbase, tid, wr_yl);
}

extern "C" void kernel_launch(void* const* d_in, const int* in_sizes, int n_in,
                              void* d_out, int out_size, void* d_ws, size_t ws_size,
                              hipStream_t stream)
{
    const float* x   = (const float*)d_in[0];
    const float* h0o = (const float*)d_in[1];
    const float* h1o = (const float*)d_in[2];
    const float* h0a = (const float*)d_in[3];
    const float* h1a = (const float*)d_in[4];
    const float* h0b = (const float*)d_in[5];
    const float* h1b = (const float*)d_in[6];

    const int nblocks = 64 * (T / TS);   // 512
    udtcwt_fused<<<nblocks, NT, 0, stream>>>(x, h0o, h1o, h0a, h1a, h0b, h1b,
                                             (float*)d_out);
}

// Round 19
// 44.819 us; speedup vs baseline: 1.0115x; 1.0115x over previous
//
#include <hip/hip_runtime.h>

// UDTCWT fully-fused r19 = r17 anchor (43.9us) + ping-pong tail:
// D>=32 levels write phi to the OTHER buffer (Q overlays dead A-tail + dead
// P stage; liveness-verified) -> phi writes inline in compute (no WAR), one
// barrier per level (was two), psi global stores overlap next level compute.
// Levels 1..16 byte-identical to anchor. LDS 79.2KiB -> still 2 blocks/CU.
// B=4, C=8 -> 16 chains, T=65536. Output: yl [4][8][T], yh [8][4][16][T].

static constexpr int B  = 4;
static constexpr int C2 = 16;
static constexpr int T  = 65536;
static constexpr int NT = 768;
static constexpr int TS = 8192;
static constexpr int HB = 1152;
static constexpr int S  = TS + 2 * HB;   // 10496 floats

// LDS layout (floats):
//   A = [0, 10496)            phi chain, in-place for lvl1..D16
//   P = [10496, 18688)        psi stage for D in {2,4,8}
//   Q = [10352, 20272)        phi ping buffer for D>=32; Qp[p]=LDS[10064+p],
//                             valid p in [288,10208). Overlays A-tail (dead
//                             during D32: A live = [144,10352)) and P (dead
//                             after last copyout, barriers before D32).
static constexpr int LDSF = 20272;       // 81088 B = 79.2 KiB <= 80 KiB

__device__ __forceinline__ float rfl(float x) {
    return __int_as_float(__builtin_amdgcn_readfirstlane(__float_as_int(x)));
}

// LDS-only barrier (measured neutral vs __syncthreads in r11).
__device__ __forceinline__ void bar_lds() {
    asm volatile("s_waitcnt lgkmcnt(0)" ::: "memory");
    __builtin_amdgcn_s_barrier();
}

// Margin chain: lvl1 out 1148; consume 4.5*D:
// 1136(D2) 1116(D4) 1080(D8) 1008(D16) 864(D32) 576(D64) 0(D128).

// ---------- Level 1 (D=1), in-place, 16 outputs (4 quads) per thread ----------
template <int SH>
__device__ __forceinline__ void f_lvl1(
    float* __restrict__ buf,
    const float* __restrict__ h0o, const float* __restrict__ h1o,
    float* __restrict__ psi_g, int gbase, int tid)
{
    float f0[5], f1[7];
#pragma unroll
    for (int k = 0; k < 5; ++k) f0[k] = rfl(h0o[k]);
#pragma unroll
    for (int k = 0; k < 7; ++k) f1[k] = rfl(h1o[k]);

    constexpr int OFF   = SH ? 1 : 2;
    constexpr int FS    = SH ? 2 : 0;
    constexpr int MO    = 1148;
    constexpr int START = HB - MO;            // 4
    constexpr int NQ    = (TS + 2 * MO) / 4;  // 2622 quads
    constexpr int G     = (NQ + 3) / 4;       // 656 threads
    const bool act = tid < G;

    int p0 = 0;
    float w[24], a[16], bb[16];
    if (act) {
        int qs = tid * 4;
        if (qs > NQ - 4) qs = NQ - 4;
        p0 = START + qs * 4;
#pragma unroll
        for (int j = 0; j < 6; ++j)
            *(float4*)&w[4 * j] = *(const float4*)&buf[p0 - 4 + 4 * j];
#pragma unroll
        for (int i = 0; i < 16; ++i) {
            float sa = 0.f, sb = 0.f;
#pragma unroll
            for (int k = 0; k < 5; ++k) sa += w[i + k + FS + OFF] * f0[k];
#pragma unroll
            for (int k = 0; k < 7; ++k) sb += w[i + k + OFF] * f1[k];
            a[i] = sa; bb[i] = sb;
        }
    }
    bar_lds();
    if (act) {
#pragma unroll
        for (int qq = 0; qq < 4; ++qq) {
            int p = p0 + qq * 4;
            if ((unsigned)(p - HB) < (unsigned)TS)
                *(float4*)&psi_g[gbase + p] =
                    make_float4(bb[4*qq], bb[4*qq+1], bb[4*qq+2], bb[4*qq+3]);
            const bool inT = (unsigned)(gbase + p) < (unsigned)T;
            *(float4*)&buf[p] = inT
                ? make_float4(a[4*qq], a[4*qq+1], a[4*qq+2], a[4*qq+3])
                : make_float4(0.f, 0.f, 0.f, 0.f);
        }
    }
    bar_lds();
}

// ---------- Dilated level, in-place (lvl D2..D16), anchor-identical ----------
template <int D, int W, int MO, bool STAGE>
__device__ __forceinline__ void f_level(
    float* __restrict__ buf, float* __restrict__ psi_st,
    const float (&f0)[10], const float (&f1)[10],
    float* __restrict__ psi_g, int gbase, int tid)
{
    constexpr int HALF  = 9 * D / 2;
    constexpr int START = HB - MO;
    constexpr int N     = TS + 2 * MO;
    static_assert(N % D == 0, "");
    constexpr int NPD   = N / D;
    constexpr int CPC   = (NPD + W - 1) / W;
    constexpr int G     = D * CPC;
    static_assert(G <= NT, "");
    constexpr int LOG2D = (D == 2 ? 1 : D == 4 ? 2 : D == 8 ? 3 : 4);

    float a[W], bb[W];
    int p0 = 0;
    const bool act = tid < G;
    if (act) {
        int r  = tid & (D - 1);
        int q  = tid >> LOG2D;
        int ms = q * W;
        if (ms > NPD - W) ms = NPD - W;
        p0 = START + r + ms * D;

        float v[W + 9];
#pragma unroll
        for (int n = 0; n < W + 9; ++n) v[n] = buf[p0 - HALF + n * D];
#pragma unroll
        for (int m = 0; m < W; ++m) { a[m] = 0.f; bb[m] = 0.f; }
#pragma unroll
        for (int k = 0; k < 10; ++k)
#pragma unroll
            for (int m = 0; m < W; ++m) {
                float x = v[m + k];
                a[m] += x * f0[k]; bb[m] += x * f1[k];
            }
    }
    bar_lds();
    if (act) {
#pragma unroll
        for (int m = 0; m < W; ++m) {
            int p = p0 + m * D;
            const bool core = (unsigned)(p - HB) < (unsigned)TS;
            if (core) {
                if constexpr (STAGE) psi_st[p - HB] = bb[m];
                else                 psi_g[gbase + p] = bb[m];
            }
            buf[p] = ((unsigned)(gbase + p) < (unsigned)T) ? a[m] : 0.f;
        }
    }
    bar_lds();
}

// ---------- Ping-pong level (D>=32): phi->dst inline, 1 barrier ----------
template <int D, int W, int MO, bool LAST>
__device__ __forceinline__ void f_ping(
    const float* __restrict__ src, float* __restrict__ dst,
    const float (&f0)[10], const float (&f1)[10],
    float* __restrict__ psi_g, float* __restrict__ yl_g,
    int gbase, int tid, bool wr_yl)
{
    constexpr int HALF  = 9 * D / 2;
    constexpr int START = HB - MO;
    constexpr int N     = TS + 2 * MO;
    static_assert(N % D == 0, "");
    constexpr int NPD   = N / D;
    constexpr int CPC   = (NPD + W - 1) / W;
    constexpr int G     = D * CPC;
    static_assert(G <= NT, "");
    constexpr int LOG2D = (D == 32 ? 5 : D == 64 ? 6 : 7);

    float a[W], bb[W];
    int p0 = 0;
    const bool act = tid < G;
    const bool do_phi = !LAST || wr_yl;     // block-uniform
    if (act) {
        int r  = tid & (D - 1);
        int q  = tid >> LOG2D;
        int ms = q * W;
        if (ms > NPD - W) ms = NPD - W;
        p0 = START + r + ms * D;

        float v[W + 9];
#pragma unroll
        for (int n = 0; n < W + 9; ++n) v[n] = src[p0 - HALF + n * D];
#pragma unroll
        for (int m = 0; m < W; ++m) { a[m] = 0.f; bb[m] = 0.f; }
        if (do_phi) {
#pragma unroll
            for (int k = 0; k < 10; ++k)
#pragma unroll
                for (int m = 0; m < W; ++m) {
                    float x = v[m + k];
                    a[m] += x * f0[k]; bb[m] += x * f1[k];
                }
        } else {
#pragma unroll
            for (int k = 0; k < 10; ++k)
#pragma unroll
                for (int m = 0; m < W; ++m) bb[m] += v[m + k] * f1[k];
        }
        if constexpr (!LAST) {
            // phi -> OTHER buffer: no WAR hazard, issue inline
#pragma unroll
            for (int m = 0; m < W; ++m) {
                int p = p0 + m * D;
                dst[p] = ((unsigned)(gbase + p) < (unsigned)T) ? a[m] : 0.f;
            }
        }
    }
    if constexpr (!LAST) {
        bar_lds();                          // dst complete; src dead
        if (act) {
            // psi -> global, overlapping NEXT level's compute (reads dst)
#pragma unroll
            for (int m = 0; m < W; ++m) {
                int p = p0 + m * D;
                if ((unsigned)(p - HB) < (unsigned)TS) psi_g[gbase + p] = bb[m];
            }
        }
    } else {
        if (act) {
#pragma unroll
            for (int m = 0; m < W; ++m) {
                int p = p0 + m * D;
                if ((unsigned)(p - HB) < (unsigned)TS) psi_g[gbase + p] = bb[m];
            }
            if (wr_yl) {
#pragma unroll
                for (int m = 0; m < W; ++m) {
                    int p = p0 + m * D;
                    if ((unsigned)(p - HB) < (unsigned)TS) yl_g[gbase + p] = a[m];
                }
            }
        }
    }
}

// Coalesced copy psi_st -> global (overlaps next level's compute phase).
__device__ __forceinline__ void f_copyout(
    const float* __restrict__ psi_st, float* __restrict__ dst, int tid)
{
    for (int i4 = tid * 4; i4 < TS; i4 += NT * 4)
        *(float4*)&dst[i4] = *(const float4*)&psi_st[i4];
}

__global__ __launch_bounds__(768, 6) void udtcwt_fused(
    const float* __restrict__ x,
    const float* __restrict__ h0o, const float* __restrict__ h1o,
    const float* __restrict__ h0a, const float* __restrict__ h1a,
    const float* __restrict__ h0b, const float* __restrict__ h1b,
    float* __restrict__ out)
{
    __shared__ float LDSb[LDSF];         // 79.2 KiB
    float* A  = LDSb;                    // [0, 10496)
    float* P  = LDSb + 10496;            // [10496, 18688)
    float* Qp = LDSb + 10064;            // Qp[p], p in [288,10208) -> [10352,20272)

    const int tid   = threadIdx.x;
    const int bid   = blockIdx.x;
    const int tile  = bid & 7;           // 8 tiles of 8192
    const int chain = bid >> 3;          // 0..63
    const int shbit = chain & 1;
    const int cx    = (chain >> 1) & 7;
    const int b     = chain >> 4;
    const int c2    = shbit * 8 + cx;
    const int t0    = tile * TS;
    const int gbase = t0 - HB;           // %4 == 0

    // stage x tile + halo (zeros outside [0,T)); all b128
    const float* xin = x + (size_t)(b * 8 + cx) * T;
    for (int i4 = tid * 4; i4 < S; i4 += NT * 4) {
        int gg = gbase + i4;
        float4 v = ((unsigned)gg < (unsigned)T)
                 ? *(const float4*)&xin[gg]
                 : make_float4(0.f, 0.f, 0.f, 0.f);
        *(float4*)&A[i4] = v;
    }

    float f0[10], f1[10];
    {
        const float* F0 = (c2 & 1) ? h0b : h0a;
        const float* F1 = (c2 & 1) ? h1b : h1a;
#pragma unroll
        for (int k = 0; k < 10; ++k) { f0[k] = rfl(F0[k]); f1[k] = rfl(F1[k]); }
    }

    float* yl_g = out + (size_t)(b * 8 + c2) * T;    // used when c2<8
    float* yh   = out + (size_t)B * 8 * T;
    const size_t LS = (size_t)B * C2 * T;
    float* psi0 = yh + (size_t)(b * C2 + c2) * T;
    const bool wr_yl = (c2 < 8);

    bar_lds();
    if (shbit) f_lvl1<1>(A, h0o, h1o, psi0, gbase, tid);
    else       f_lvl1<0>(A, h0o, h1o, psi0, gbase, tid);

    f_level<  2, 15, 1136, true >(A, P, f0, f1, nullptr,        gbase, tid);
    f_copyout(P, psi0 + 1 * LS + t0, tid);
    f_level<  4, 15, 1116, true >(A, P, f0, f1, nullptr,        gbase, tid);
    f_copyout(P, psi0 + 2 * LS + t0, tid);
    f_level<  8, 15, 1080, true >(A, P, f0, f1, nullptr,        gbase, tid);
    f_copyout(P, psi0 + 3 * LS + t0, tid);
    f_level< 16, 15, 1008, false>(A, P, f0, f1, psi0 + 4 * LS,  gbase, tid);

    // ping-pong tail: A -> Q -> A, one barrier per level
    f_ping< 32, 15,  864, false>(A,  Qp, f0, f1, psi0 + 5 * LS, nullptr, gbase, tid, false);
    f_ping< 64, 15,  576, false>(Qp, A,  f0, f1, psi0 + 6 * LS, nullptr, gbase, tid, false);
    f_ping<128, 15,    0, true >(A,  nullptr, f0, f1, psi0 + 7 * LS, yl_g, gbase, tid, wr_yl);
}

extern "C" void kernel_launch(void* const* d_in, const int* in_sizes, int n_in,
                              void* d_out, int out_size, void* d_ws, size_t ws_size,
                              hipStream_t stream)
{
    const float* x   = (const float*)d_in[0];
    const float* h0o = (const float*)d_in[1];
    const float* h1o = (const float*)d_in[2];
    const float* h0a = (const float*)d_in[3];
    const float* h1a = (const float*)d_in[4];
    const float* h0b = (const float*)d_in[5];
    const float* h1b = (const float*)d_in[6];

    const int nblocks = 64 * (T / TS);   // 512
    udtcwt_fused<<<nblocks, NT, 0, stream>>>(x, h0o, h1o, h0a, h1a, h0b, h1b,
                                             (float*)d_out);
}

// Round 20
// 42.707 us; speedup vs baseline: 1.0615x; 1.0495x over previous
//
#include <hip/hip_runtime.h>

// UDTCWT fully-fused r20 = r17 anchor (43.9us) + ONE change: f_lvl1 quad
// INTERLEAVING (qi = tid + r*NT). Anchor's blocked mapping had 64B lane
// stride -> ~16-32-way LDS bank conflicts (r16 PMC: 3.7M conflict cycles)
// and 2x-scattered global psi stores. Interleaved: 16B lane stride ->
// conflict-free b128, coalesced psi. All else byte-identical to anchor.
// B=4, C=8 -> 16 chains, T=65536. Output: yl [4][8][T], yh [8][4][16][T].

static constexpr int B  = 4;
static constexpr int C2 = 16;
static constexpr int T  = 65536;
static constexpr int NT = 768;
static constexpr int TS = 8192;
static constexpr int HB = 1152;
static constexpr int S  = TS + 2 * HB;   // 10496 floats = 41.98 KB

__device__ __forceinline__ float rfl(float x) {
    return __int_as_float(__builtin_amdgcn_readfirstlane(__float_as_int(x)));
}

// LDS-only barrier (measured neutral vs __syncthreads in r11).
__device__ __forceinline__ void bar_lds() {
    asm volatile("s_waitcnt lgkmcnt(0)" ::: "memory");
    __builtin_amdgcn_s_barrier();
}

// Margin chain: lvl1 out 1148; each dilated level consumes 4.5*D:
// 1136(D2) 1116(D4) 1080(D8) 1008(D16) 864(D32) 576(D64) 0(D128).

// ---------- Level 1 (D=1), in-place, INTERLEAVED quads ----------
// Thread handles quads qi = tid + r*NT, r=0..3 (NQ=2622 <= 4*768; tail
// threads clamp to last quad -> duplicate identical writes, benign).
// Per quad: window [p-4, p+8) via 3 conflict-free b128 reads; tap indices
// identical to anchor: phi w[i+k+FS+OFF], psi w[i+k+OFF], w[j]=x[p-4+j].
template <int SH>
__device__ __forceinline__ void f_lvl1(
    float* __restrict__ buf,
    const float* __restrict__ h0o, const float* __restrict__ h1o,
    float* __restrict__ psi_g, int gbase, int tid)
{
    float f0[5], f1[7];
#pragma unroll
    for (int k = 0; k < 5; ++k) f0[k] = rfl(h0o[k]);
#pragma unroll
    for (int k = 0; k < 7; ++k) f1[k] = rfl(h1o[k]);

    constexpr int OFF   = SH ? 1 : 2;
    constexpr int FS    = SH ? 2 : 0;
    constexpr int MO    = 1148;
    constexpr int START = HB - MO;            // 4 (%4==0)
    constexpr int NQ    = (TS + 2 * MO) / 4;  // 2622 quads
    constexpr int NR    = 4;                  // rounds (4*768 >= 2622)

    float a[NR][4], bb[NR][4];
#pragma unroll
    for (int r = 0; r < NR; ++r) {
        int qi = tid + r * NT; if (qi > NQ - 1) qi = NQ - 1;  // clamp, benign
        int p  = START + qi * 4;
        float w[12];
        *(float4*)&w[0] = *(const float4*)&buf[p - 4];
        *(float4*)&w[4] = *(const float4*)&buf[p];
        *(float4*)&w[8] = *(const float4*)&buf[p + 4];
#pragma unroll
        for (int i = 0; i < 4; ++i) {
            float sa = 0.f, sb = 0.f;
#pragma unroll
            for (int k = 0; k < 5; ++k) sa += w[i + k + FS + OFF] * f0[k];
#pragma unroll
            for (int k = 0; k < 7; ++k) sb += w[i + k + OFF] * f1[k];
            a[r][i] = sa; bb[r][i] = sb;
        }
    }
    bar_lds();
#pragma unroll
    for (int r = 0; r < NR; ++r) {
        int qi = tid + r * NT; if (qi > NQ - 1) qi = NQ - 1;
        int p  = START + qi * 4;              // %4==0
        if ((unsigned)(p - HB) < (unsigned)TS)
            *(float4*)&psi_g[gbase + p] =
                make_float4(bb[r][0], bb[r][1], bb[r][2], bb[r][3]);
        const bool inT = (unsigned)(gbase + p) < (unsigned)T;
        *(float4*)&buf[p] = inT
            ? make_float4(a[r][0], a[r][1], a[r][2], a[r][3])
            : make_float4(0.f, 0.f, 0.f, 0.f);
    }
    bar_lds();
}

// ---------- Dilated level, in-place; STAGE -> psi via LDS stage buffer ----------
template <int D, int W, int MO, bool STAGE, bool LAST>
__device__ __forceinline__ void f_level(
    float* __restrict__ buf, float* __restrict__ psi_st,
    const float (&f0)[10], const float (&f1)[10],
    float* __restrict__ psi_g, float* __restrict__ yl_g,
    int gbase, int tid, bool wr_yl)
{
    constexpr int HALF  = 9 * D / 2;
    constexpr int START = HB - MO;
    constexpr int N     = TS + 2 * MO;
    static_assert(N % D == 0, "");
    constexpr int NPD   = N / D;
    constexpr int CPC   = (NPD + W - 1) / W;
    constexpr int G     = D * CPC;
    static_assert(G <= NT, "single chunk per thread required");
    constexpr int LOG2D = (D == 2 ? 1 : D == 4 ? 2 : D == 8 ? 3 :
                           D == 16 ? 4 : D == 32 ? 5 : D == 64 ? 6 : 7);

    float a[W], bb[W];
    int p0 = 0;
    const bool act = tid < G;
    const bool do_phi = !LAST || wr_yl;     // block-uniform
    if (act) {
        int r  = tid & (D - 1);
        int q  = tid >> LOG2D;
        int ms = q * W;
        if (ms > NPD - W) ms = NPD - W;     // clamp (dup work, benign)
        p0 = START + r + ms * D;

        float v[W + 9];
#pragma unroll
        for (int n = 0; n < W + 9; ++n) v[n] = buf[p0 - HALF + n * D];
#pragma unroll
        for (int m = 0; m < W; ++m) { a[m] = 0.f; bb[m] = 0.f; }
        if (do_phi) {
#pragma unroll
            for (int k = 0; k < 10; ++k)
#pragma unroll
                for (int m = 0; m < W; ++m) {
                    float x = v[m + k];
                    a[m] += x * f0[k]; bb[m] += x * f1[k];
                }
        } else {
#pragma unroll
            for (int k = 0; k < 10; ++k)
#pragma unroll
                for (int m = 0; m < W; ++m) bb[m] += v[m + k] * f1[k];
        }
    }
    bar_lds();
    if (act) {
#pragma unroll
        for (int m = 0; m < W; ++m) {
            int p = p0 + m * D;
            const bool core = (unsigned)(p - HB) < (unsigned)TS;
            if (core) {
                if constexpr (STAGE) psi_st[p - HB] = bb[m];
                else                 psi_g[gbase + p] = bb[m];
            }
            if constexpr (!LAST) {
                buf[p] = ((unsigned)(gbase + p) < (unsigned)T) ? a[m] : 0.f;
            } else {
                if (wr_yl && core) yl_g[gbase + p] = a[m];
            }
        }
    }
    bar_lds();
}

// Coalesced copy psi_st -> global (overlaps next level's compute phase).
__device__ __forceinline__ void f_copyout(
    const float* __restrict__ psi_st, float* __restrict__ dst, int tid)
{
    for (int i4 = tid * 4; i4 < TS; i4 += NT * 4)
        *(float4*)&dst[i4] = *(const float4*)&psi_st[i4];
}

__global__ __launch_bounds__(768, 6) void udtcwt_fused(
    const float* __restrict__ x,
    const float* __restrict__ h0o, const float* __restrict__ h1o,
    const float* __restrict__ h0a, const float* __restrict__ h1a,
    const float* __restrict__ h0b, const float* __restrict__ h1b,
    float* __restrict__ out)
{
    __shared__ float A[S];       // 41.98 KB, in-place phi chain
    __shared__ float P[TS];      // 32 KB psi stage

    const int tid   = threadIdx.x;
    const int bid   = blockIdx.x;
    const int tile  = bid & 7;           // 8 tiles of 8192
    const int chain = bid >> 3;          // 0..63
    const int shbit = chain & 1;
    const int cx    = (chain >> 1) & 7;
    const int b     = chain >> 4;
    const int c2    = shbit * 8 + cx;
    const int t0    = tile * TS;
    const int gbase = t0 - HB;           // %4 == 0

    // stage x tile + halo (zeros outside [0,T)); all b128
    const float* xin = x + (size_t)(b * 8 + cx) * T;
    for (int i4 = tid * 4; i4 < S; i4 += NT * 4) {
        int gg = gbase + i4;             // quad fully in or out of [0,T)
        float4 v = ((unsigned)gg < (unsigned)T)
                 ? *(const float4*)&xin[gg]
                 : make_float4(0.f, 0.f, 0.f, 0.f);
        *(float4*)&A[i4] = v;
    }

    float f0[10], f1[10];
    {
        const float* F0 = (c2 & 1) ? h0b : h0a;
        const float* F1 = (c2 & 1) ? h1b : h1a;
#pragma unroll
        for (int k = 0; k < 10; ++k) { f0[k] = rfl(F0[k]); f1[k] = rfl(F1[k]); }
    }

    float* yl_g = out + (size_t)(b * 8 + c2) * T;    // used when c2<8
    float* yh   = out + (size_t)B * 8 * T;
    const size_t LS = (size_t)B * C2 * T;
    float* psi0 = yh + (size_t)(b * C2 + c2) * T;
    const bool wr_yl = (c2 < 8);

    bar_lds();
    if (shbit) f_lvl1<1>(A, h0o, h1o, psi0, gbase, tid);
    else       f_lvl1<0>(A, h0o, h1o, psi0, gbase, tid);

    f_level<  2, 15, 1136, true,  false>(A, P, f0, f1, nullptr, nullptr, gbase, tid, false);
    f_copyout(P, psi0 + 1 * LS + t0, tid);
    f_level<  4, 15, 1116, true,  false>(A, P, f0, f1, nullptr, nullptr, gbase, tid, false);
    f_copyout(P, psi0 + 2 * LS + t0, tid);
    f_level<  8, 15, 1080, true,  false>(A, P, f0, f1, nullptr, nullptr, gbase, tid, false);
    f_copyout(P, psi0 + 3 * LS + t0, tid);
    f_level< 16, 15, 1008, false, false>(A, P, f0, f1, psi0 + 4 * LS, nullptr, gbase, tid, false);
    f_level< 32, 15,  864, false, false>(A, P, f0, f1, psi0 + 5 * LS, nullptr, gbase, tid, false);
    f_level< 64, 15,  576, false, false>(A, P, f0, f1, psi0 + 6 * LS, nullptr, gbase, tid, false);
    f_level<128, 15,    0, false, true >(A, P, f0, f1, psi0 + 7 * LS, yl_g,    gbase, tid, wr_yl);
}

extern "C" void kernel_launch(void* const* d_in, const int* in_sizes, int n_in,
                              void* d_out, int out_size, void* d_ws, size_t ws_size,
                              hipStream_t stream)
{
    const float* x   = (const float*)d_in[0];
    const float* h0o = (const float*)d_in[1];
    const float* h1o = (const float*)d_in[2];
    const float* h0a = (const float*)d_in[3];
    const float* h1a = (const float*)d_in[4];
    const float* h0b = (const float*)d_in[5];
    const float* h1b = (const float*)d_in[6];

    const int nblocks = 64 * (T / TS);   // 512
    udtcwt_fused<<<nblocks, NT, 0, stream>>>(x, h0o, h1o, h0a, h1a, h0b, h1b,
                                             (float*)d_out);
}

// Round 21
// 40.462 us; speedup vs baseline: 1.1204x; 1.0555x over previous
//
#include <hip/hip_runtime.h>

// UDTCWT fully-fused r21 = r20 (42.7us) + ONE change: lvl1 computes DIRECTLY
// from global x (x is L3-resident; 3 aligned float4 loads per quad), writing
// phi inline into the dead A buffer (no WAR -> no staging pass, 2 fewer
// barriers, no lvl1 LDS reads). Levels D>=2 byte-identical to r20.
// B=4, C=8 -> 16 chains, T=65536. Output: yl [4][8][T], yh [8][4][16][T].

static constexpr int B  = 4;
static constexpr int C2 = 16;
static constexpr int T  = 65536;
static constexpr int NT = 768;
static constexpr int TS = 8192;
static constexpr int HB = 1152;
static constexpr int S  = TS + 2 * HB;   // 10496 floats = 41.98 KB

__device__ __forceinline__ float rfl(float x) {
    return __int_as_float(__builtin_amdgcn_readfirstlane(__float_as_int(x)));
}

// LDS-only barrier (measured neutral vs __syncthreads in r11).
__device__ __forceinline__ void bar_lds() {
    asm volatile("s_waitcnt lgkmcnt(0)" ::: "memory");
    __builtin_amdgcn_s_barrier();
}

// Margin chain: lvl1 out 1148; each dilated level consumes 4.5*D:
// 1136(D2) 1116(D4) 1080(D8) 1008(D16) 864(D32) 576(D64) 0(D128).

// ---------- Level 1 (D=1), DIRECT from global, interleaved quads ----------
// Per round: 3 aligned float4 global loads (window [p-4,p+8)), compute
// phi/psi, phi float4 -> A[p] inline (A dead until now; no barrier needed),
// psi float4 -> global (core quads). Taps identical to r20:
// phi w[i+k+FS+OFF], psi w[i+k+OFF], w[j] = x[p-4+j].
template <int SH>
__device__ __forceinline__ void f_lvl1(
    const float* __restrict__ xin, float* __restrict__ A,
    const float* __restrict__ h0o, const float* __restrict__ h1o,
    float* __restrict__ psi_g, int gbase, int tid)
{
    float f0[5], f1[7];
#pragma unroll
    for (int k = 0; k < 5; ++k) f0[k] = rfl(h0o[k]);
#pragma unroll
    for (int k = 0; k < 7; ++k) f1[k] = rfl(h1o[k]);

    constexpr int OFF   = SH ? 1 : 2;
    constexpr int FS    = SH ? 2 : 0;
    constexpr int MO    = 1148;
    constexpr int START = HB - MO;            // 4 (%4==0)
    constexpr int NQ    = (TS + 2 * MO) / 4;  // 2622 quads
    constexpr int NR    = 4;                  // 4*768 >= 2622

#pragma unroll
    for (int r = 0; r < NR; ++r) {
        int qi = tid + r * NT; if (qi > NQ - 1) qi = NQ - 1;  // clamp, benign
        int p  = START + qi * 4;
        float w[12];
#pragma unroll
        for (int j = 0; j < 3; ++j) {
            int gg = gbase + p - 4 + 4 * j;   // %4==0: quad fully in or out
            *(float4*)&w[4 * j] = ((unsigned)gg < (unsigned)T)
                ? *(const float4*)&xin[gg]
                : make_float4(0.f, 0.f, 0.f, 0.f);
        }
        float a[4], bb[4];
#pragma unroll
        for (int i = 0; i < 4; ++i) {
            float sa = 0.f, sb = 0.f;
#pragma unroll
            for (int k = 0; k < 5; ++k) sa += w[i + k + FS + OFF] * f0[k];
#pragma unroll
            for (int k = 0; k < 7; ++k) sb += w[i + k + OFF] * f1[k];
            a[i] = sa; bb[i] = sb;
        }
        const bool inT = (unsigned)(gbase + p) < (unsigned)T;
        *(float4*)&A[p] = inT ? make_float4(a[0], a[1], a[2], a[3])
                              : make_float4(0.f, 0.f, 0.f, 0.f);
        if ((unsigned)(p - HB) < (unsigned)TS)
            *(float4*)&psi_g[gbase + p] = make_float4(bb[0], bb[1], bb[2], bb[3]);
    }
}

// ---------- Dilated level, in-place; STAGE -> psi via LDS stage buffer ----------
template <int D, int W, int MO, bool STAGE, bool LAST>
__device__ __forceinline__ void f_level(
    float* __restrict__ buf, float* __restrict__ psi_st,
    const float (&f0)[10], const float (&f1)[10],
    float* __restrict__ psi_g, float* __restrict__ yl_g,
    int gbase, int tid, bool wr_yl)
{
    constexpr int HALF  = 9 * D / 2;
    constexpr int START = HB - MO;
    constexpr int N     = TS + 2 * MO;
    static_assert(N % D == 0, "");
    constexpr int NPD   = N / D;
    constexpr int CPC   = (NPD + W - 1) / W;
    constexpr int G     = D * CPC;
    static_assert(G <= NT, "single chunk per thread required");
    constexpr int LOG2D = (D == 2 ? 1 : D == 4 ? 2 : D == 8 ? 3 :
                           D == 16 ? 4 : D == 32 ? 5 : D == 64 ? 6 : 7);

    float a[W], bb[W];
    int p0 = 0;
    const bool act = tid < G;
    const bool do_phi = !LAST || wr_yl;     // block-uniform
    if (act) {
        int r  = tid & (D - 1);
        int q  = tid >> LOG2D;
        int ms = q * W;
        if (ms > NPD - W) ms = NPD - W;     // clamp (dup work, benign)
        p0 = START + r + ms * D;

        float v[W + 9];
#pragma unroll
        for (int n = 0; n < W + 9; ++n) v[n] = buf[p0 - HALF + n * D];
#pragma unroll
        for (int m = 0; m < W; ++m) { a[m] = 0.f; bb[m] = 0.f; }
        if (do_phi) {
#pragma unroll
            for (int k = 0; k < 10; ++k)
#pragma unroll
                for (int m = 0; m < W; ++m) {
                    float x = v[m + k];
                    a[m] += x * f0[k]; bb[m] += x * f1[k];
                }
        } else {
#pragma unroll
            for (int k = 0; k < 10; ++k)
#pragma unroll
                for (int m = 0; m < W; ++m) bb[m] += v[m + k] * f1[k];
        }
    }
    bar_lds();
    if (act) {
#pragma unroll
        for (int m = 0; m < W; ++m) {
            int p = p0 + m * D;
            const bool core = (unsigned)(p - HB) < (unsigned)TS;
            if (core) {
                if constexpr (STAGE) psi_st[p - HB] = bb[m];
                else                 psi_g[gbase + p] = bb[m];
            }
            if constexpr (!LAST) {
                buf[p] = ((unsigned)(gbase + p) < (unsigned)T) ? a[m] : 0.f;
            } else {
                if (wr_yl && core) yl_g[gbase + p] = a[m];
            }
        }
    }
    bar_lds();
}

// Coalesced copy psi_st -> global (overlaps next level's compute phase).
__device__ __forceinline__ void f_copyout(
    const float* __restrict__ psi_st, float* __restrict__ dst, int tid)
{
    for (int i4 = tid * 4; i4 < TS; i4 += NT * 4)
        *(float4*)&dst[i4] = *(const float4*)&psi_st[i4];
}

__global__ __launch_bounds__(768, 6) void udtcwt_fused(
    const float* __restrict__ x,
    const float* __restrict__ h0o, const float* __restrict__ h1o,
    const float* __restrict__ h0a, const float* __restrict__ h1a,
    const float* __restrict__ h0b, const float* __restrict__ h1b,
    float* __restrict__ out)
{
    __shared__ float A[S];       // 41.98 KB, in-place phi chain
    __shared__ float P[TS];      // 32 KB psi stage

    const int tid   = threadIdx.x;
    const int bid   = blockIdx.x;
    const int tile  = bid & 7;           // 8 tiles of 8192
    const int chain = bid >> 3;          // 0..63
    const int shbit = chain & 1;
    const int cx    = (chain >> 1) & 7;
    const int b     = chain >> 4;
    const int c2    = shbit * 8 + cx;
    const int t0    = tile * TS;
    const int gbase = t0 - HB;           // %4 == 0

    const float* xin = x + (size_t)(b * 8 + cx) * T;

    float f0[10], f1[10];
    {
        const float* F0 = (c2 & 1) ? h0b : h0a;
        const float* F1 = (c2 & 1) ? h1b : h1a;
#pragma unroll
        for (int k = 0; k < 10; ++k) { f0[k] = rfl(F0[k]); f1[k] = rfl(F1[k]); }
    }

    float* yl_g = out + (size_t)(b * 8 + c2) * T;    // used when c2<8
    float* yh   = out + (size_t)B * 8 * T;
    const size_t LS = (size_t)B * C2 * T;
    float* psi0 = yh + (size_t)(b * C2 + c2) * T;
    const bool wr_yl = (c2 < 8);

    // lvl1 straight from global; phi lands in A inline (A dead before this)
    if (shbit) f_lvl1<1>(xin, A, h0o, h1o, psi0, gbase, tid);
    else       f_lvl1<0>(xin, A, h0o, h1o, psi0, gbase, tid);
    bar_lds();                           // A visible to all waves

    f_level<  2, 15, 1136, true,  false>(A, P, f0, f1, nullptr, nullptr, gbase, tid, false);
    f_copyout(P, psi0 + 1 * LS + t0, tid);
    f_level<  4, 15, 1116, true,  false>(A, P, f0, f1, nullptr, nullptr, gbase, tid, false);
    f_copyout(P, psi0 + 2 * LS + t0, tid);
    f_level<  8, 15, 1080, true,  false>(A, P, f0, f1, nullptr, nullptr, gbase, tid, false);
    f_copyout(P, psi0 + 3 * LS + t0, tid);
    f_level< 16, 15, 1008, false, false>(A, P, f0, f1, psi0 + 4 * LS, nullptr, gbase, tid, false);
    f_level< 32, 15,  864, false, false>(A, P, f0, f1, psi0 + 5 * LS, nullptr, gbase, tid, false);
    f_level< 64, 15,  576, false, false>(A, P, f0, f1, psi0 + 6 * LS, nullptr, gbase, tid, false);
    f_level<128, 15,    0, false, true >(A, P, f0, f1, psi0 + 7 * LS, yl_g,    gbase, tid, wr_yl);
}

extern "C" void kernel_launch(void* const* d_in, const int* in_sizes, int n_in,
                              void* d_out, int out_size, void* d_ws, size_t ws_size,
                              hipStream_t stream)
{
    const float* x   = (const float*)d_in[0];
    const float* h0o = (const float*)d_in[1];
    const float* h1o = (const float*)d_in[2];
    const float* h0a = (const float*)d_in[3];
    const float* h1a = (const float*)d_in[4];
    const float* h0b = (const float*)d_in[5];
    const float* h1b = (const float*)d_in[6];

    const int nblocks = 64 * (T / TS);   // 512
    udtcwt_fused<<<nblocks, NT, 0, stream>>>(x, h0o, h1o, h0a, h1a, h0b, h1b,
                                             (float*)d_out);
}